// Round 1
// baseline (161.621 us; speedup 1.0000x reference)
//
#include <hip/hip_runtime.h>

// Problem constants
//   m1:(1,1,4096,64) m2:(1,1,6144,64) m3:(1,1,8192,64) m4:(1,1,4096,64) fp32
//   WQ_w:(3,64,64) WQ_b:(3,64) WK_w:(4,3,64,64) WK_b:(4,3,64)
//   out:(1,4096,32) fp32
//
// Workspace layout (floats):
//   Q_T  [64][4096]                      @ 0          (262144)
//   K_T  per module [64][T_m]            @ 262144     (1441792)  base = 262144 + 64*rowoff[m]
//   SP   356 slots x 2048 (d*32+e)       @ 1703936    (729088)   slot stride 2048
// total 2433024 floats = 9.28 MB

#define QT_OFF   0
#define KT_OFF   262144
#define SP_OFF   1703936

__global__ __launch_bounds__(256) void k_mlp(
    const float* __restrict__ x0, const float* __restrict__ x1,
    const float* __restrict__ x2, const float* __restrict__ x3,
    const float* __restrict__ wq_w, const float* __restrict__ wq_b,
    const float* __restrict__ wk_w, const float* __restrict__ wk_b,
    float* __restrict__ ws)
{
    __shared__ float sW[3*64*64];   // 48 KB
    __shared__ float sB[3*64];
    __shared__ float sH[64*65];     // h[d][r], padded

    const int tid = threadIdx.x;
    const int bid = blockIdx.x;

    // tasks: 0=Q (64 blocks), 1..4 = K_m (64,96,128,64 blocks)
    int task, rb;
    if (bid < 64)       { task = 0; rb = bid; }
    else if (bid < 128) { task = 1; rb = bid - 64; }
    else if (bid < 224) { task = 2; rb = bid - 128; }
    else if (bid < 352) { task = 3; rb = bid - 224; }
    else                { task = 4; rb = bid - 352; }

    const float* Xs[4] = {x0, x1, x2, x3};
    const int Tm[4]     = {4096, 6144, 8192, 4096};
    const int rowoff[4] = {0, 4096, 10240, 18432};

    const float* X; const float* W; const float* Bv;
    float* outT; int stride;
    if (task == 0) {
        X = x0; W = wq_w; Bv = wq_b;
        outT = ws + QT_OFF; stride = 4096;
    } else {
        int m = task - 1;
        X = Xs[m]; W = wk_w + m*3*64*64; Bv = wk_b + m*3*64;
        outT = ws + KT_OFF + 64*rowoff[m]; stride = Tm[m];
    }

    for (int i = tid; i < 3*64*64; i += 256) sW[i] = W[i];
    for (int i = tid; i < 3*64;   i += 256) sB[i] = Bv[i];

    const int row0 = rb * 64;
    // stage 64 input rows into sH[d][r], coalesced global loads
    const float4* X4 = (const float4*)(X + row0*64);
    #pragma unroll
    for (int k = 0; k < 4; ++k) {
        int idx = k*256 + tid;          // float4 index in 64x64 tile
        float4 v = X4[idx];
        int db = idx * 4;
        int d0 = db & 63;
        int rr = db >> 6;
        sH[(d0+0)*65 + rr] = v.x;
        sH[(d0+1)*65 + rr] = v.y;
        sH[(d0+2)*65 + rr] = v.z;
        sH[(d0+3)*65 + rr] = v.w;
    }
    __syncthreads();

    const int r  = tid & 63;      // row within tile (wave lanes = consecutive rows)
    const int q  = tid >> 6;      // column quarter (wave-uniform)
    const int cb = q * 16;

    float a[16];
    #pragma unroll
    for (int l = 0; l < 3; ++l) {
        const float* Wl = sW + l*4096;
        #pragma unroll
        for (int c = 0; c < 16; ++c) a[c] = sB[l*64 + cb + c];
        for (int d = 0; d < 64; ++d) {
            float hd = sH[d*65 + r];            // conflict-free (pad 65)
            #pragma unroll
            for (int c = 0; c < 16; ++c)        // broadcast LDS reads, b128-able
                a[c] += hd * Wl[d*64 + cb + c];
        }
        if (l < 2) {
            #pragma unroll
            for (int c = 0; c < 16; ++c) a[c] = fmaxf(a[c], 0.0f);
            __syncthreads();
            #pragma unroll
            for (int c = 0; c < 16; ++c) sH[(cb+c)*65 + r] = a[c];
            __syncthreads();
        }
    }
    // store transposed: out[d][row], coalesced across lanes (r consecutive)
    #pragma unroll
    for (int c = 0; c < 16; ++c)
        outT[(size_t)(cb+c)*stride + row0 + r] = a[c];
}

// One block per SP slot. slot 0 = zeros; slot s>=1 holds sum over chunk (s-1)
// of K_j V_j^T (entry layout d*32+e). 356 blocks total.
__global__ __launch_bounds__(256) void k_chunks(
    const float* __restrict__ x0, const float* __restrict__ x1,
    const float* __restrict__ x2, const float* __restrict__ x3,
    float* __restrict__ ws)
{
    __shared__ float kb[64*65];   // K[d][j], padded
    __shared__ float vb[64*32];   // V[j][e]
    const int tid = threadIdx.x;
    const int bid = blockIdx.x;

    int m, slot;
    if (bid < 65)       { m = 0; slot = bid; }
    else if (bid < 162) { m = 1; slot = bid - 65; }
    else if (bid < 291) { m = 2; slot = bid - 162; }
    else                { m = 3; slot = bid - 291; }

    const int spoff[4]  = {0, 65, 162, 291};
    const int Tm[4]     = {4096, 6144, 8192, 4096};
    const int rowoff[4] = {0, 4096, 10240, 18432};
    const float* Xs[4]  = {x0, x1, x2, x3};

    float* base = ws + SP_OFF + (size_t)(spoff[m] + slot) * 2048;
    if (slot == 0) {
        for (int i = tid; i < 2048; i += 256) base[i] = 0.0f;
        return;
    }
    const int b  = slot - 1;
    const int j0 = b * 64;
    const int T  = Tm[m];
    const float* Kt = ws + KT_OFF + 64*rowoff[m];
    const float* X  = Xs[m];

    for (int idx = tid; idx < 4096; idx += 256) {
        int d = idx >> 6, j = idx & 63;
        kb[d*65 + j] = Kt[(size_t)d*T + j0 + j];   // coalesced (j contiguous)
    }
    for (int idx = tid; idx < 2048; idx += 256) {
        int j = idx >> 5, e = idx & 31;
        vb[idx] = X[(size_t)(j0 + j)*64 + e];
    }
    __syncthreads();

    const int e  = tid & 31;
    const int dg = tid >> 5;     // 0..7, d-group of 8
    float acc[8] = {0,0,0,0,0,0,0,0};
    for (int j = 0; j < 64; ++j) {
        float v = vb[j*32 + e];
        #pragma unroll
        for (int u = 0; u < 8; ++u)
            acc[u] += kb[(dg*8+u)*65 + j] * v;
    }
    #pragma unroll
    for (int u = 0; u < 8; ++u)
        base[(dg*8+u)*32 + e] = acc[u];   // coalesced-ish (e contiguous)
}

// In-place inclusive scan over slots -> slot b ends up holding exclusive
// prefix sum of chunks < b. 32 blocks: (module, entry-block of 256).
__global__ __launch_bounds__(256) void k_prefix(float* __restrict__ ws)
{
    const int nslots[4] = {65, 97, 129, 65};
    const int spoff[4]  = {0, 65, 162, 291};
    const int m = blockIdx.x >> 3;
    const int entry = (blockIdx.x & 7)*256 + threadIdx.x;
    float* p = ws + SP_OFF + (size_t)spoff[m]*2048 + entry;
    const int n = nslots[m];
    float s = 0.0f;
    #pragma unroll 4
    for (int k = 0; k < n; ++k) {
        float v = p[(size_t)k*2048];
        s += v;
        p[(size_t)k*2048] = s;
    }
}

// Block per query (4096 blocks); wave w handles module w.
__global__ __launch_bounds__(256) void k_query(
    const float* __restrict__ x0, const float* __restrict__ x1,
    const float* __restrict__ x2, const float* __restrict__ x3,
    const float* __restrict__ ws, float* __restrict__ out)
{
    __shared__ float red[4][32];
    const int tid  = threadIdx.x;
    const int i    = blockIdx.x;
    const int m    = tid >> 6;       // module (wave-uniform)
    const int lane = tid & 63;
    const int e    = lane & 31;
    const int h    = lane >> 5;

    const float* Xs[4] = {x0, x1, x2, x3};
    const int Tm[4]     = {4096, 6144, 8192, 4096};
    const int rowoff[4] = {0, 4096, 10240, 18432};
    const int spoff[4]  = {0, 65, 162, 291};

    const float* X = Xs[m];
    const int T = Tm[m];
    const float t = x0[(size_t)i*64 + 63];   // t1[i]

    // c = #{ j : t2[j] <= t }  (t2 sorted; uniform scalar binary search)
    int lo = 0, hi = T;
    while (lo < hi) {
        int mid = (lo + hi) >> 1;
        if (X[(size_t)mid*64 + 63] <= t) lo = mid + 1; else hi = mid;
    }
    const int c   = lo;
    const int b   = c >> 6;
    const int rem = c & 63;

    const float* Qt = ws + QT_OFF;                         // [64][4096]
    const float* Kt = ws + KT_OFF + 64*rowoff[m];          // [64][T]
    const float* sp = ws + SP_OFF + (size_t)(spoff[m] + b)*2048;

    float acc = 0.0f;
    // state part: lanes (e, h); half-wave h covers d in [h*32, h*32+32)
    #pragma unroll 8
    for (int dd = 0; dd < 32; ++dd) {
        int d = h*32 + dd;
        float qd = Qt[(size_t)d*4096 + i];    // wave-uniform -> scalar load
        acc += qd * sp[d*32 + e];             // coalesced 128B x2
    }
    if (rem > 0) {
        const int jb = b * 64;
        // lane-parallel dots: s[l] = Q_i . K_{jb+l}; K_T reads coalesced
        float s = 0.0f;
        #pragma unroll 8
        for (int d = 0; d < 64; ++d)
            s += Qt[(size_t)d*4096 + i] * Kt[(size_t)d*T + jb + lane];
        // accumulate: half-wave h handles l = 2u+h
        const int nu = (rem + 1) >> 1;
        for (int u = 0; u < nu; ++u) {
            int lh = 2*u + h;
            float sl = __shfl(s, lh, 64);
            float v  = X[(size_t)(jb + lh)*64 + e];  // in-bounds: jb+lh <= c < T
            if (lh < rem) acc += sl * v;
        }
    }
    acc += __shfl_xor(acc, 32, 64);
    if (lane < 32) red[m][lane] = acc;
    __syncthreads();
    if (tid < 32)
        out[(size_t)i*32 + tid] = red[0][tid] + red[1][tid] + red[2][tid] + red[3][tid];
}

extern "C" void kernel_launch(void* const* d_in, const int* in_sizes, int n_in,
                              void* d_out, int out_size, void* d_ws, size_t ws_size,
                              hipStream_t stream) {
    const float* x0   = (const float*)d_in[0];
    const float* x1   = (const float*)d_in[1];
    const float* x2   = (const float*)d_in[2];
    const float* x3   = (const float*)d_in[3];
    const float* wq_w = (const float*)d_in[4];
    const float* wq_b = (const float*)d_in[5];
    const float* wk_w = (const float*)d_in[6];
    const float* wk_b = (const float*)d_in[7];
    float* ws  = (float*)d_ws;
    float* out = (float*)d_out;

    hipLaunchKernelGGL(k_mlp,    dim3(416),  dim3(256), 0, stream,
                       x0, x1, x2, x3, wq_w, wq_b, wk_w, wk_b, ws);
    hipLaunchKernelGGL(k_chunks, dim3(356),  dim3(256), 0, stream,
                       x0, x1, x2, x3, ws);
    hipLaunchKernelGGL(k_prefix, dim3(32),   dim3(256), 0, stream, ws);
    hipLaunchKernelGGL(k_query,  dim3(4096), dim3(256), 0, stream,
                       x0, x1, x2, x3, ws, out);
}

// Round 2
// 148.567 us; speedup vs baseline: 1.0879x; 1.0879x over previous
//
#include <hip/hip_runtime.h>

// Problem constants
//   m1:(1,1,4096,64) m2:(1,1,6144,64) m3:(1,1,8192,64) m4:(1,1,4096,64) fp32
//   WQ_w:(3,64,64) WQ_b:(3,64) WK_w:(4,3,64,64) WK_b:(4,3,64)
//   out:(1,4096,32) fp32
//
// Workspace layout (floats):
//   Q_T  [64][4096]                      @ 0          (262144)
//   K_T  per module [64][T_m]            @ 262144     (1441792)
//   SP   356 slots x 2048 (d*32+e)       @ 1703936    (729088)
//   TD   dense t2 per module             @ 2433024    (22528)
//   C    c-table int[4][4096]            @ 2455552    (16384)
// total 2471936 floats = 9.43 MB

#define QT_OFF   0
#define KT_OFF   262144
#define SP_OFF   1703936
#define TD_OFF   2433024
#define C_OFF    2455552

// ---------------------------------------------------------------------------
// MLP: 128-row tiles, 2 rows/thread; W staged one layer at a time (16 KB).
// Also extracts dense t-arrays (X[:,63]) into ws[TD_OFF..].
// Tiles: Q:32 | K m0:32 | m1:48 | m2:64 | m3:32  -> 208 blocks.
__global__ __launch_bounds__(256) void k_mlp(
    const float* __restrict__ x0, const float* __restrict__ x1,
    const float* __restrict__ x2, const float* __restrict__ x3,
    const float* __restrict__ wq_w, const float* __restrict__ wq_b,
    const float* __restrict__ wk_w, const float* __restrict__ wk_b,
    float* __restrict__ ws)
{
    __shared__ float sW[64*64];    // one layer, 16 KB
    __shared__ float sH[64*130];   // h[d][r], 128 rows, pad 130 (2-way only)

    const int tid = threadIdx.x;
    const int bid = blockIdx.x;

    int task, rb;
    if (bid < 32)       { task = 0; rb = bid; }
    else if (bid < 64)  { task = 1; rb = bid - 32; }
    else if (bid < 112) { task = 2; rb = bid - 64; }
    else if (bid < 176) { task = 3; rb = bid - 112; }
    else                { task = 4; rb = bid - 176; }

    const float* Xs[4] = {x0, x1, x2, x3};
    const int Tm[4]     = {4096, 6144, 8192, 4096};
    const int rowoff[4] = {0, 4096, 10240, 18432};

    const float* X; const float* W; const float* Bv;
    float* outT; int stride; int mm = -1;
    if (task == 0) {
        X = x0; W = wq_w; Bv = wq_b;
        outT = ws + QT_OFF; stride = 4096;
    } else {
        mm = task - 1;
        X = Xs[mm]; W = wk_w + mm*3*64*64; Bv = wk_b + mm*3*64;
        outT = ws + KT_OFF + 64*rowoff[mm]; stride = Tm[mm];
    }

    const int row0 = rb * 128;
    const float4* X4 = (const float4*)(X + (size_t)row0*64);
    #pragma unroll
    for (int k = 0; k < 8; ++k) {
        int idx = k*256 + tid;            // float4 index in 128x64 tile
        float4 v = X4[idx];
        int db = idx * 4;
        int d0 = db & 63;
        int rr = db >> 6;                 // 0..127
        sH[(d0+0)*130 + rr] = v.x;
        sH[(d0+1)*130 + rr] = v.y;
        sH[(d0+2)*130 + rr] = v.z;
        sH[(d0+3)*130 + rr] = v.w;
    }
    __syncthreads();
    // dense t extraction (K tasks cover all modules; module 0's t == t1)
    if (task > 0 && tid < 128)
        ws[TD_OFF + rowoff[mm] + row0 + tid] = sH[63*130 + tid];

    const int r  = tid & 63;
    const int q  = tid >> 6;
    const int cb = q * 16;

    float a0[16], a1[16];
    #pragma unroll 1
    for (int l = 0; l < 3; ++l) {
        __syncthreads();                  // prev compute done -> safe to overwrite sW
        const float4* W4 = (const float4*)(W + l*4096);
        #pragma unroll
        for (int k = 0; k < 4; ++k)
            ((float4*)sW)[k*256 + tid] = W4[k*256 + tid];
        __syncthreads();

        #pragma unroll
        for (int c = 0; c < 16; ++c) {
            float b = Bv[l*64 + cb + c];
            a0[c] = b; a1[c] = b;
        }
        for (int d = 0; d < 64; ++d) {
            float h0 = sH[d*130 + r];
            float h1 = sH[d*130 + 64 + r];
            #pragma unroll
            for (int c = 0; c < 16; ++c) {
                float w = sW[d*64 + cb + c];   // wave-uniform broadcast, b128-able
                a0[c] += h0 * w;
                a1[c] += h1 * w;
            }
        }
        if (l < 2) {
            #pragma unroll
            for (int c = 0; c < 16; ++c) {
                a0[c] = fmaxf(a0[c], 0.0f);
                a1[c] = fmaxf(a1[c], 0.0f);
            }
            __syncthreads();              // compute reads of sH done before overwrite
            #pragma unroll
            for (int c = 0; c < 16; ++c) {
                sH[(cb+c)*130 + r]      = a0[c];
                sH[(cb+c)*130 + 64 + r] = a1[c];
            }
        }
    }
    #pragma unroll
    for (int c = 0; c < 16; ++c) {
        outT[(size_t)(cb+c)*stride + row0 + r]      = a0[c];
        outT[(size_t)(cb+c)*stride + row0 + 64 + r] = a1[c];
    }
}

// ---------------------------------------------------------------------------
// All 4x4096 searchsorted counts in parallel against dense t arrays.
__global__ __launch_bounds__(256) void k_cidx(float* __restrict__ ws)
{
    const int g = blockIdx.x * 256 + threadIdx.x;   // 64 blocks
    const int m = g >> 12, i = g & 4095;
    const int Tm[4]     = {4096, 6144, 8192, 4096};
    const int rowoff[4] = {0, 4096, 10240, 18432};
    const float* td = ws + TD_OFF;
    const float t = td[i];                          // t1[i]
    const float* t2 = td + rowoff[m];
    int lo = 0, hi = Tm[m];
    while (lo < hi) {
        int mid = (lo + hi) >> 1;
        if (t2[mid] <= t) lo = mid + 1; else hi = mid;
    }
    ((int*)(ws + C_OFF))[g] = lo;
}

// ---------------------------------------------------------------------------
// One block per SP slot (356). Thread owns (d, e-group of 8); K via 1 b32,
// V via 2 broadcast b128 per j. LDS-transposed store for coalesced writes.
__global__ __launch_bounds__(256) void k_chunks(
    const float* __restrict__ x0, const float* __restrict__ x1,
    const float* __restrict__ x2, const float* __restrict__ x3,
    float* __restrict__ ws)
{
    __shared__ float kb[64*65];   // K[d][j]
    __shared__ float vb[64*32];   // V[j][e]
    __shared__ float so[64*33];   // out transpose staging
    const int tid = threadIdx.x;
    const int bid = blockIdx.x;

    int m, slot;
    if (bid < 65)       { m = 0; slot = bid; }
    else if (bid < 162) { m = 1; slot = bid - 65; }
    else if (bid < 291) { m = 2; slot = bid - 162; }
    else                { m = 3; slot = bid - 291; }

    const int spoff[4]  = {0, 65, 162, 291};
    const int Tm[4]     = {4096, 6144, 8192, 4096};
    const int rowoff[4] = {0, 4096, 10240, 18432};
    const float* Xs[4]  = {x0, x1, x2, x3};

    float* base = ws + SP_OFF + (size_t)(spoff[m] + slot) * 2048;
    if (slot == 0) {
        for (int i = tid; i < 2048; i += 256) base[i] = 0.0f;
        return;
    }
    const int b  = slot - 1;
    const int j0 = b * 64;
    const int T  = Tm[m];
    const float* Kt = ws + KT_OFF + 64*rowoff[m];
    const float* X  = Xs[m];

    for (int idx = tid; idx < 4096; idx += 256) {
        int d = idx >> 6, j = idx & 63;
        kb[d*65 + j] = Kt[(size_t)d*T + j0 + j];
    }
    for (int idx = tid; idx < 2048; idx += 256) {
        int j = idx >> 5, e = idx & 31;
        vb[idx] = X[(size_t)(j0 + j)*64 + e];
    }
    __syncthreads();

    const int d  = tid & 63;
    const int eg = tid >> 6;          // 0..3 (wave-uniform)
    float acc[8] = {0,0,0,0,0,0,0,0};
    const float4* vb4 = (const float4*)vb;
    for (int j = 0; j < 64; ++j) {
        float  kd = kb[d*65 + j];             // stride-65 -> conflict-free
        float4 vA = vb4[j*8 + eg*2 + 0];      // broadcast b128
        float4 vB = vb4[j*8 + eg*2 + 1];
        acc[0] += kd * vA.x; acc[1] += kd * vA.y;
        acc[2] += kd * vA.z; acc[3] += kd * vA.w;
        acc[4] += kd * vB.x; acc[5] += kd * vB.y;
        acc[6] += kd * vB.z; acc[7] += kd * vB.w;
    }
    #pragma unroll
    for (int u = 0; u < 8; ++u)
        so[d*33 + eg*8 + u] = acc[u];
    __syncthreads();
    for (int idx = tid; idx < 2048; idx += 256)
        base[idx] = so[(idx >> 5)*33 + (idx & 31)];
}

// ---------------------------------------------------------------------------
// In-place scan over slots. 128 blocks x 64 threads (one thread per chain).
__global__ __launch_bounds__(64) void k_prefix(float* __restrict__ ws)
{
    const int nslots[4] = {65, 97, 129, 65};
    const int spoff[4]  = {0, 65, 162, 291};
    const int m = blockIdx.x >> 5;
    const int entry = (blockIdx.x & 31)*64 + threadIdx.x;
    float* p = ws + SP_OFF + (size_t)spoff[m]*2048 + entry;
    const int n = nslots[m];
    float s = 0.0f;
    #pragma unroll 8
    for (int k = 0; k < n; ++k) {
        float v = p[(size_t)k*2048];
        s += v;
        p[(size_t)k*2048] = s;
    }
}

// ---------------------------------------------------------------------------
// Block per query; wave m handles module m. XCD-swizzled so each XCD gets a
// contiguous time range (queries are time-sorted) -> 1/8 of SP/K_T/X per XCD.
__global__ __launch_bounds__(256) void k_query(
    const float* __restrict__ x0, const float* __restrict__ x1,
    const float* __restrict__ x2, const float* __restrict__ x3,
    const float* __restrict__ ws, float* __restrict__ out)
{
    __shared__ float red[4][32];
    const int tid  = threadIdx.x;
    const int bid  = blockIdx.x;
    const int i    = ((bid & 7) << 9) | (bid >> 3);   // XCD swizzle
    const int m    = tid >> 6;
    const int lane = tid & 63;
    const int e    = lane & 31;
    const int h    = lane >> 5;

    const float* Xs[4] = {x0, x1, x2, x3};
    const int Tm[4]     = {4096, 6144, 8192, 4096};
    const int rowoff[4] = {0, 4096, 10240, 18432};
    const int spoff[4]  = {0, 65, 162, 291};

    const float* X = Xs[m];
    const int T = Tm[m];

    const int c   = ((const int*)(ws + C_OFF))[m*4096 + i];
    const int b   = c >> 6;
    const int rem = c & 63;

    const float* Qt = ws + QT_OFF;
    const float* Kt = ws + KT_OFF + 64*rowoff[m];
    const float* sp = ws + SP_OFF + (size_t)(spoff[m] + b)*2048;

    float acc = 0.0f;
    #pragma unroll 8
    for (int dd = 0; dd < 32; ++dd) {
        int d = h*32 + dd;
        float qd = Qt[(size_t)d*4096 + i];    // wave-uniform -> scalar load
        acc += qd * sp[d*32 + e];
    }
    if (rem > 0) {
        const int jb = b * 64;
        float s = 0.0f;
        if (lane < rem) {                      // only fetch K rows we need
            #pragma unroll 8
            for (int d = 0; d < 64; ++d)
                s += Qt[(size_t)d*4096 + i] * Kt[(size_t)d*T + jb + lane];
        }
        const int nu = (rem + 1) >> 1;
        #pragma unroll 4
        for (int u = 0; u < nu; ++u) {
            int lh = 2*u + h;
            float sl = __shfl(s, lh, 64);
            if (lh < rem) acc += sl * X[(size_t)(jb + lh)*64 + e];
        }
    }
    acc += __shfl_xor(acc, 32, 64);
    if (lane < 32) red[m][lane] = acc;
    __syncthreads();
    if (tid < 32)
        out[(size_t)i*32 + tid] = red[0][tid] + red[1][tid] + red[2][tid] + red[3][tid];
}

extern "C" void kernel_launch(void* const* d_in, const int* in_sizes, int n_in,
                              void* d_out, int out_size, void* d_ws, size_t ws_size,
                              hipStream_t stream) {
    const float* x0   = (const float*)d_in[0];
    const float* x1   = (const float*)d_in[1];
    const float* x2   = (const float*)d_in[2];
    const float* x3   = (const float*)d_in[3];
    const float* wq_w = (const float*)d_in[4];
    const float* wq_b = (const float*)d_in[5];
    const float* wk_w = (const float*)d_in[6];
    const float* wk_b = (const float*)d_in[7];
    float* ws  = (float*)d_ws;
    float* out = (float*)d_out;

    hipLaunchKernelGGL(k_mlp,    dim3(208),  dim3(256), 0, stream,
                       x0, x1, x2, x3, wq_w, wq_b, wk_w, wk_b, ws);
    hipLaunchKernelGGL(k_cidx,   dim3(64),   dim3(256), 0, stream, ws);
    hipLaunchKernelGGL(k_chunks, dim3(356),  dim3(256), 0, stream,
                       x0, x1, x2, x3, ws);
    hipLaunchKernelGGL(k_prefix, dim3(128),  dim3(64),  0, stream, ws);
    hipLaunchKernelGGL(k_query,  dim3(4096), dim3(256), 0, stream,
                       x0, x1, x2, x3, ws, out);
}